// Round 2
// baseline (323.855 us; speedup 1.0000x reference)
//
#include <hip/hip_runtime.h>
#include <hip/hip_bf16.h>

// NestedAttnProcessor: B=2, HW=4096, hid=1280, cad=2048, Ltxt=77, NT=4, H=20, D=64.
// Inputs/outputs are FP32 (per reference). Internally: convert to bf16, run MFMA
// pipeline, fp32 epilogue on the final GEMM.
// Pipeline: cvt(hs,enc) -> transpose+cvt weights -> q GEMM -> kv GEMMs -> fused attn -> out GEMM(+bias, fp32).
// Attention fold: out = sum_{t!=s} w_t v_t + w_s * sum_j wn_j vn_j  (w_s v_s cancels).

typedef unsigned short ushort_t;
typedef __attribute__((ext_vector_type(8))) short short8;
typedef __attribute__((ext_vector_type(4))) float f32x4;

#define B_   2
#define HW_  4096
#define HID_ 1280
#define CAD_ 2048
#define LTXT 77
#define NTOK 4
#define NH_  20
#define HD_  64

__device__ __forceinline__ ushort_t f2bf(float f) {
    __hip_bfloat16 h = __float2bfloat16(f);
    return *reinterpret_cast<ushort_t*>(&h);
}

__device__ __forceinline__ void gld_lds16(const void* g, void* l) {
    __builtin_amdgcn_global_load_lds(
        (const __attribute__((address_space(1))) unsigned int*)g,
        (__attribute__((address_space(3))) unsigned int*)l,
        16, 0, 0);
}

// ---------------- fp32 -> bf16 elementwise (n % 4 == 0) ----------------
__global__ __launch_bounds__(256) void cvt_f32_bf16(
    const float* __restrict__ src, ushort_t* __restrict__ dst, int n4)
{
    int i = blockIdx.x * 256 + threadIdx.x;
    if (i >= n4) return;
    float4 v = *(const float4*)(src + (size_t)i * 4);
    ushort_t o[4] = { f2bf(v.x), f2bf(v.y), f2bf(v.z), f2bf(v.w) };
    *(uint2*)(dst + (size_t)i * 4) = *(uint2*)o;
}

// ------------- weight transpose+cvt: fp32 (K,1280) -> bf16 (1280,K) -------------
__global__ __launch_bounds__(256) void transpose6(
    const float* __restrict__ s0, const float* __restrict__ s1,
    const float* __restrict__ s2, const float* __restrict__ s3,
    const float* __restrict__ s4, const float* __restrict__ s5,
    ushort_t* __restrict__ d0, ushort_t* __restrict__ d1,
    ushort_t* __restrict__ d2, ushort_t* __restrict__ d3,
    ushort_t* __restrict__ d4, ushort_t* __restrict__ d5)
{
    int z = blockIdx.y;
    const float* S; ushort_t* D; int K_;
    switch (z) {
        case 0: S = s0; D = d0; K_ = 1280; break;
        case 1: S = s1; D = d1; K_ = 2048; break;
        case 2: S = s2; D = d2; K_ = 2048; break;
        case 3: S = s3; D = d3; K_ = 2048; break;
        case 4: S = s4; D = d4; K_ = 2048; break;
        default: S = s5; D = d5; K_ = 1280; break;
    }
    int tr = blockIdx.x / 40, tc = blockIdx.x % 40;
    if (tr >= K_ / 32) return;       // block-uniform early-out (no barrier hazard)
    __shared__ ushort_t tl[32][33];
    int t = threadIdx.x;
    int c = t & 31, r0 = t >> 5;
#pragma unroll
    for (int i = 0; i < 4; i++) {
        int r = r0 + i * 8;
        tl[r][c] = f2bf(S[(size_t)(tr * 32 + r) * 1280 + tc * 32 + c]);
    }
    __syncthreads();
#pragma unroll
    for (int i = 0; i < 4; i++) {
        int r = r0 + i * 8;
        D[(size_t)(tc * 32 + r) * K_ + tr * 32 + c] = tl[c][r];
    }
}

// ---------------- bf16 MFMA GEMM, B^T layout (N,K), N=ldc=1280 ----------------
// 128x128 tile, 4 waves (2x2 of 64x64), BK=32, global_load_lds width 16.
template <bool F32OUT>
__device__ __forceinline__ void gemm_body(
    const ushort_t* __restrict__ A, const ushort_t* __restrict__ Bt,
    void* __restrict__ Cout, const float* __restrict__ biasf,
    int M, int K, int lda, int row0, int col0)
{
    __shared__ ushort_t lsA[128 * 32];
    __shared__ ushort_t lsB[128 * 32];
    const int t = threadIdx.x;
    const int w = t >> 6, l = t & 63;
    const int mb = (w >> 1) * 64, nb = (w & 1) * 64;
    const int lrow = l & 15, lk = (l >> 4) * 8;
    f32x4 acc[4][4] = {};
    for (int k0 = 0; k0 < K; k0 += 32) {
        __syncthreads();   // protect LDS from prior-iteration readers
#pragma unroll
        for (int p = 0; p < 2; p++) {
            int lin = p * 256 + t;
            int r = lin >> 2, cc = (lin & 3) * 8;
            int ra = row0 + r; if (ra > M - 1) ra = M - 1;  // clamp (masked at store)
            gld_lds16(A + (size_t)ra * lda + k0 + cc, &lsA[lin * 8]);
            int rb = col0 + r;                               // N=1280, always in-bounds
            gld_lds16(Bt + (size_t)rb * K + k0 + cc, &lsB[lin * 8]);
        }
        __syncthreads();   // drains vmcnt -> LDS tiles visible
        short8 af[4], bfr[4];
#pragma unroll
        for (int mt = 0; mt < 4; mt++)
            af[mt] = *(const short8*)&lsA[(mb + mt * 16 + lrow) * 32 + lk];
#pragma unroll
        for (int nt = 0; nt < 4; nt++)
            bfr[nt] = *(const short8*)&lsB[(nb + nt * 16 + lrow) * 32 + lk];
#pragma unroll
        for (int mt = 0; mt < 4; mt++)
#pragma unroll
            for (int nt = 0; nt < 4; nt++)
                acc[mt][nt] = __builtin_amdgcn_mfma_f32_16x16x32_bf16(
                    af[mt], bfr[nt], acc[mt][nt], 0, 0, 0);
    }
    const int quad = l >> 4, cl = l & 15;
#pragma unroll
    for (int nt = 0; nt < 4; nt++) {
        int col = col0 + nb + nt * 16 + cl;
        float bv = biasf ? biasf[col] : 0.f;
#pragma unroll
        for (int mt = 0; mt < 4; mt++)
#pragma unroll
            for (int r = 0; r < 4; r++) {
                int row = row0 + mb + mt * 16 + quad * 4 + r;
                if (row < M) {
                    if (F32OUT)
                        ((float*)Cout)[(size_t)row * 1280 + col] = acc[mt][nt][r] + bv;
                    else
                        ((ushort_t*)Cout)[(size_t)row * 1280 + col] = f2bf(acc[mt][nt][r] + bv);
                }
            }
    }
}

__global__ __launch_bounds__(256) void gemm_bt_bf16(
    const ushort_t* __restrict__ A, const ushort_t* __restrict__ Bt,
    ushort_t* __restrict__ C, int M, int K, int lda)
{
    gemm_body<false>(A, Bt, C, nullptr, M, K, lda, blockIdx.x * 128, blockIdx.y * 128);
}

__global__ __launch_bounds__(256) void gemm_bt_f32(
    const ushort_t* __restrict__ A, const ushort_t* __restrict__ Bt,
    float* __restrict__ C, const float* __restrict__ biasf, int M, int K, int lda)
{
    gemm_body<true>(A, Bt, C, biasf, M, K, lda, blockIdx.x * 128, blockIdx.y * 128);
}

// grid.z = 8 jobs: z<4: (b=z>>1, kind=z&1) txt rows with Wk/Wv (M=77);
//                  z>=4: nested img rows with Wk_nest/Wv_nest (M=4).
__global__ __launch_bounds__(256) void gemm_kv(
    const ushort_t* __restrict__ enc,
    const ushort_t* __restrict__ WkT, const ushort_t* __restrict__ WvT,
    const ushort_t* __restrict__ WknT, const ushort_t* __restrict__ WvnT,
    ushort_t* __restrict__ kb, ushort_t* __restrict__ vb,
    ushort_t* __restrict__ knb, ushort_t* __restrict__ vnb)
{
    int z = blockIdx.z;
    int kind = z & 1;
    const ushort_t* A; const ushort_t* Bt; ushort_t* C; int M;
    if (z < 4) {
        int bb = z >> 1;
        M = LTXT;
        A = enc + (size_t)bb * (LTXT + NTOK) * CAD_;
        Bt = kind ? WvT : WkT;
        C = (kind ? vb : kb) + (size_t)bb * LTXT * HID_;
    } else {
        int bb = (z - 4) >> 1;
        M = NTOK;
        A = enc + ((size_t)bb * (LTXT + NTOK) + LTXT) * CAD_;
        Bt = kind ? WvnT : WknT;
        C = (kind ? vnb : knb) + (size_t)bb * NTOK * HID_;
    }
    gemm_body<false>(A, Bt, C, nullptr, M, CAD_, CAD_, blockIdx.x * 128, blockIdx.y * 128);
}

// ---------------- fused attention ----------------
// grid: (HW/128, NH, B). block 256 (4 waves x 32 queries).
// 96 padded keys: [0,77)=txt, [77,80)=zero, [80,84)=nested, [84,96)=zero.
__global__ __launch_bounds__(256) void attn_kernel(
    const ushort_t* __restrict__ qb, const ushort_t* __restrict__ kbf,
    const ushort_t* __restrict__ vbf, const ushort_t* __restrict__ knb,
    const ushort_t* __restrict__ vnb, const int* __restrict__ sidx,
    ushort_t* __restrict__ ob)
{
    const int qt = blockIdx.x, h = blockIdx.y, b = blockIdx.z;
    const int t = threadIdx.x, w = t >> 6, l = t & 63;
    const int s_idx = sidx[b];
    __shared__ ushort_t Kl[96 * 72];    // key-major, stride 72 (pad kills bank conflicts)
    __shared__ ushort_t VT[64 * 104];   // dim-major (V^T), stride 104
    __shared__ ushort_t QP[128 * 104];  // Q phase: stride 72; P phase: stride 104

    // fill K (16B chunks)
    for (int id = t; id < 96 * 8; id += 256) {
        int key = id >> 3, c = (id & 7) * 8;
        uint4 v;
        if (key < LTXT)
            v = *(const uint4*)&kbf[((size_t)(b * LTXT + key)) * HID_ + h * HD_ + c];
        else if (key >= 80 && key < 80 + NTOK)
            v = *(const uint4*)&knb[((size_t)(b * NTOK + key - 80)) * HID_ + h * HD_ + c];
        else
            v = make_uint4(0u, 0u, 0u, 0u);
        *(uint4*)&Kl[key * 72 + c] = v;
    }
    // fill V^T (scalar; data is L1/L2 hot across q-tiles)
    for (int id = t; id < 64 * 96; id += 256) {
        int d = id / 96, key = id - d * 96;
        ushort_t val = 0;
        if (key < LTXT)
            val = vbf[((size_t)(b * LTXT + key)) * HID_ + h * HD_ + d];
        else if (key >= 80 && key < 80 + NTOK)
            val = vnb[((size_t)(b * NTOK + key - 80)) * HID_ + h * HD_ + d];
        VT[d * 104 + key] = val;
    }
    // fill Q tile (stride 72)
    const int q0 = qt * 128;
    for (int id = t; id < 128 * 8; id += 256) {
        int r = id >> 3, c = (id & 7) * 8;
        uint4 v = *(const uint4*)&qb[((size_t)(b * HW_ + q0 + r)) * HID_ + h * HD_ + c];
        *(uint4*)&QP[r * 72 + c] = v;
    }
    __syncthreads();

    const int mbw = w * 32, lrow = l & 15, lk = (l >> 4) * 8;
    const int quad = l >> 4, cl = l & 15;

    // S = Q K^T  (M=32 per wave, N=96, K=64)
    f32x4 S[2][6] = {};
#pragma unroll
    for (int ks = 0; ks < 2; ks++) {
        short8 af0 = *(const short8*)&QP[(mbw + lrow) * 72 + ks * 32 + lk];
        short8 af1 = *(const short8*)&QP[(mbw + 16 + lrow) * 72 + ks * 32 + lk];
#pragma unroll
        for (int nt = 0; nt < 6; nt++) {
            short8 bf = *(const short8*)&Kl[(nt * 16 + lrow) * 72 + ks * 32 + lk];
            S[0][nt] = __builtin_amdgcn_mfma_f32_16x16x32_bf16(af0, bf, S[0][nt], 0, 0, 0);
            S[1][nt] = __builtin_amdgcn_mfma_f32_16x16x32_bf16(af1, bf, S[1][nt], 0, 0, 0);
        }
    }
    __syncthreads();  // everyone done reading Q before P overwrites the buffer

    const float sc = 0.125f;
#pragma unroll
    for (int mt = 0; mt < 2; mt++) {
#pragma unroll
        for (int r = 0; r < 4; r++) {
            float v[6];
#pragma unroll
            for (int nt = 0; nt < 6; nt++) v[nt] = S[mt][nt][r] * sc;
            // main softmax over cols [0,77)
            float m = -1e30f;
#pragma unroll
            for (int nt = 0; nt < 5; nt++) {
                int c = nt * 16 + cl;
                if (c < LTXT) m = fmaxf(m, v[nt]);
            }
#pragma unroll
            for (int off = 1; off < 16; off <<= 1) m = fmaxf(m, __shfl_xor(m, off));
            float e[5], lsum = 0.f, wsn = 0.f;
#pragma unroll
            for (int nt = 0; nt < 5; nt++) {
                int c = nt * 16 + cl;
                float ev = (c < LTXT) ? __expf(v[nt] - m) : 0.f;
                e[nt] = ev; lsum += ev;
                if (c == s_idx) wsn += ev;
            }
#pragma unroll
            for (int off = 1; off < 16; off <<= 1) {
                lsum += __shfl_xor(lsum, off);
                wsn  += __shfl_xor(wsn, off);
            }
            float inv = 1.f / lsum;
            float ws = wsn * inv;   // softmax weight at key s
            // nested softmax over 4 keys (frag 5, lanes cl<4)
            bool nv = (cl < 4);
            float m5 = nv ? v[5] : -1e30f;
#pragma unroll
            for (int off = 1; off < 16; off <<= 1) m5 = fmaxf(m5, __shfl_xor(m5, off));
            float e5 = nv ? __expf(v[5] - m5) : 0.f;
            float l5 = e5;
#pragma unroll
            for (int off = 1; off < 16; off <<= 1) l5 += __shfl_xor(l5, off);
            float p5 = ws * e5 / l5;
            int row = mbw + mt * 16 + quad * 4 + r;
#pragma unroll
            for (int nt = 0; nt < 5; nt++) {
                int c = nt * 16 + cl;
                float p = (c < LTXT && c != s_idx) ? e[nt] * inv : 0.f;
                QP[row * 104 + c] = f2bf(p);
            }
            QP[row * 104 + 80 + cl] = f2bf(p5);
        }
    }
    __syncthreads();

    // O = P @ Vc  (M=32 per wave, N=64, K=96)
    f32x4 O[2][4] = {};
#pragma unroll
    for (int ks = 0; ks < 3; ks++) {
        short8 af0 = *(const short8*)&QP[(mbw + lrow) * 104 + ks * 32 + lk];
        short8 af1 = *(const short8*)&QP[(mbw + 16 + lrow) * 104 + ks * 32 + lk];
#pragma unroll
        for (int nt = 0; nt < 4; nt++) {
            short8 bf = *(const short8*)&VT[(nt * 16 + lrow) * 104 + ks * 32 + lk];
            O[0][nt] = __builtin_amdgcn_mfma_f32_16x16x32_bf16(af0, bf, O[0][nt], 0, 0, 0);
            O[1][nt] = __builtin_amdgcn_mfma_f32_16x16x32_bf16(af1, bf, O[1][nt], 0, 0, 0);
        }
    }
#pragma unroll
    for (int mt = 0; mt < 2; mt++)
#pragma unroll
        for (int nt = 0; nt < 4; nt++)
#pragma unroll
            for (int r = 0; r < 4; r++) {
                int row = mbw + mt * 16 + quad * 4 + r;
                int d = nt * 16 + cl;
                ob[((size_t)(b * HW_ + q0 + row)) * HID_ + h * HD_ + d] = f2bf(O[mt][nt][r]);
            }
}

// ---------------- launch ----------------
extern "C" void kernel_launch(void* const* d_in, const int* in_sizes, int n_in,
                              void* d_out, int out_size, void* d_ws, size_t ws_size,
                              hipStream_t stream) {
    const float* hs   = (const float*)d_in[0];
    const float* enc  = (const float*)d_in[1];
    const int*   idx  = (const int*)d_in[2];
    const float* Wq   = (const float*)d_in[3];
    const float* Wk   = (const float*)d_in[4];
    const float* Wv   = (const float*)d_in[5];
    const float* Wkn  = (const float*)d_in[6];
    const float* Wvn  = (const float*)d_in[7];
    const float* Wout = (const float*)d_in[8];
    const float* bout = (const float*)d_in[9];
    float* out = (float*)d_out;

    ushort_t* ws = (ushort_t*)d_ws;
    size_t o = 0;
    ushort_t* WqT   = ws + o; o += (size_t)1280 * 1280;
    ushort_t* WkT   = ws + o; o += (size_t)1280 * 2048;
    ushort_t* WvT   = ws + o; o += (size_t)1280 * 2048;
    ushort_t* WknT  = ws + o; o += (size_t)1280 * 2048;
    ushort_t* WvnT  = ws + o; o += (size_t)1280 * 2048;
    ushort_t* WoutT = ws + o; o += (size_t)1280 * 1280;
    ushort_t* hsb   = ws + o; o += (size_t)B_ * HW_ * HID_;   // bf16 hidden_states
    ushort_t* encb  = ws + o; o += (size_t)B_ * (LTXT + NTOK) * CAD_;
    ushort_t* qbuf  = ws + o; o += (size_t)B_ * HW_ * HID_;
    ushort_t* kbuf  = ws + o; o += (size_t)B_ * LTXT * HID_;
    ushort_t* vbuf  = ws + o; o += (size_t)B_ * LTXT * HID_;
    ushort_t* knbuf = ws + o; o += (size_t)B_ * NTOK * HID_;
    ushort_t* vnbuf = ws + o; o += (size_t)B_ * NTOK * HID_;
    ushort_t* attnb = hsb;  // alias: hsb dead after the Q GEMM

    int n4_hs  = (B_ * HW_ * HID_) / 4;                  // 2,621,440
    int n4_enc = (B_ * (LTXT + NTOK) * CAD_) / 4;        // 82,944
    cvt_f32_bf16<<<dim3((n4_hs + 255) / 256), 256, 0, stream>>>(hs, hsb, n4_hs);
    cvt_f32_bf16<<<dim3((n4_enc + 255) / 256), 256, 0, stream>>>(enc, encb, n4_enc);
    transpose6<<<dim3(2560, 6), 256, 0, stream>>>(Wq, Wk, Wv, Wkn, Wvn, Wout,
                                                  WqT, WkT, WvT, WknT, WvnT, WoutT);
    gemm_bt_bf16<<<dim3(64, 10), 256, 0, stream>>>(hsb, WqT, qbuf,
                                                   B_ * HW_, HID_, HID_);
    gemm_kv<<<dim3(1, 10, 8), 256, 0, stream>>>(encb, WkT, WvT, WknT, WvnT,
                                                kbuf, vbuf, knbuf, vnbuf);
    attn_kernel<<<dim3(HW_ / 128, NH_, B_), 256, 0, stream>>>(qbuf, kbuf, vbuf,
                                                              knbuf, vnbuf, idx, attnb);
    gemm_bt_f32<<<dim3(64, 10), 256, 0, stream>>>(attnb, WoutT, out, bout,
                                                  B_ * HW_, HID_, HID_);
}

// Round 4
// 286.185 us; speedup vs baseline: 1.1316x; 1.1316x over previous
//
#include <hip/hip_runtime.h>
#include <hip/hip_bf16.h>

// NestedAttnProcessor: B=2, HW=4096, hid=1280, cad=2048, Ltxt=77, NT=4, H=20, D=64.
// FP32 in/out; bf16 MFMA internally.
// 4 launches: prep(cvt+transpose) -> gemm_q_kv -> attn -> out GEMM.
// Attention fold: out = sum_{t!=s} w_t v_t + w_s * sum_j wn_j vn_j.
// R4 fixes vs R3: (1) prep cvt branches are grid-stride (R3 converted only 1/4 of hs);
//                 (2) VT stride restored to 104 (key extent is 96; 72 truncated it).

typedef unsigned short ushort_t;
typedef __attribute__((ext_vector_type(8))) short short8;
typedef __attribute__((ext_vector_type(4))) float f32x4;

#define B_   2
#define HW_  4096
#define HID_ 1280
#define CAD_ 2048
#define LTXT 77
#define NTOK 4
#define NH_  20
#define HD_  64

__device__ __forceinline__ ushort_t f2bf(float f) {
    __hip_bfloat16 h = __float2bfloat16(f);
    return *reinterpret_cast<ushort_t*>(&h);
}

__device__ __forceinline__ void gld_lds16(const void* g, void* l) {
    __builtin_amdgcn_global_load_lds(
        (const __attribute__((address_space(1))) unsigned int*)g,
        (__attribute__((address_space(3))) unsigned int*)l,
        16, 0, 0);
}

// ---------------- prep: cvt hs, cvt enc, transpose+cvt 6 weights ----------------
// grid (2560, 8): y=0 hs cvt (grid-stride), y=1 enc cvt (grid-stride),
//                 y=2..7 weight transpose (z=y-2).
__global__ __launch_bounds__(256) void prep(
    const float* __restrict__ hs, const float* __restrict__ enc,
    const float* __restrict__ s0, const float* __restrict__ s1,
    const float* __restrict__ s2, const float* __restrict__ s3,
    const float* __restrict__ s4, const float* __restrict__ s5,
    ushort_t* __restrict__ hsb, ushort_t* __restrict__ encb,
    ushort_t* __restrict__ d0, ushort_t* __restrict__ d1,
    ushort_t* __restrict__ d2, ushort_t* __restrict__ d3,
    ushort_t* __restrict__ d4, ushort_t* __restrict__ d5)
{
    const int y = blockIdx.y, t = threadIdx.x;
    if (y <= 1) {
        const float* src = y ? enc : hs;
        ushort_t* dst = y ? encb : hsb;
        int n4 = y ? (B_ * (LTXT + NTOK) * CAD_) / 4 : (B_ * HW_ * HID_) / 4;
        int step = gridDim.x * 256;
        for (int i = blockIdx.x * 256 + t; i < n4; i += step) {
            float4 v = *(const float4*)(src + (size_t)i * 4);
            ushort_t o[4] = { f2bf(v.x), f2bf(v.y), f2bf(v.z), f2bf(v.w) };
            *(uint2*)(dst + (size_t)i * 4) = *(uint2*)o;
        }
        return;
    }
    int z = y - 2;
    const float* S; ushort_t* D; int K_;
    switch (z) {
        case 0: S = s0; D = d0; K_ = 1280; break;
        case 1: S = s1; D = d1; K_ = 2048; break;
        case 2: S = s2; D = d2; K_ = 2048; break;
        case 3: S = s3; D = d3; K_ = 2048; break;
        case 4: S = s4; D = d4; K_ = 2048; break;
        default: S = s5; D = d5; K_ = 1280; break;
    }
    int tr = blockIdx.x / 40, tc = blockIdx.x % 40;
    if (tr >= K_ / 32) return;       // block-uniform early-out (before any barrier)
    __shared__ ushort_t tl[32][33];
    int c = t & 31, r0 = t >> 5;
#pragma unroll
    for (int i = 0; i < 4; i++) {
        int r = r0 + i * 8;
        tl[r][c] = f2bf(S[(size_t)(tr * 32 + r) * 1280 + tc * 32 + c]);
    }
    __syncthreads();
#pragma unroll
    for (int i = 0; i < 4; i++) {
        int r = r0 + i * 8;
        D[(size_t)(tc * 32 + r) * K_ + tr * 32 + c] = tl[c][r];
    }
}

// ---------------- bf16 MFMA GEMM body, B^T layout (N,K), ldc=1280 ----------------
template <bool F32OUT>
__device__ __forceinline__ void gemm_body(
    const ushort_t* __restrict__ A, const ushort_t* __restrict__ Bt,
    void* __restrict__ Cout, const float* __restrict__ biasf,
    int M, int K, int lda, int row0, int col0)
{
    __shared__ ushort_t lsA[128 * 32];
    __shared__ ushort_t lsB[128 * 32];
    const int t = threadIdx.x;
    const int w = t >> 6, l = t & 63;
    const int mb = (w >> 1) * 64, nb = (w & 1) * 64;
    const int lrow = l & 15, lk = (l >> 4) * 8;
    f32x4 acc[4][4] = {};
    for (int k0 = 0; k0 < K; k0 += 32) {
        __syncthreads();
#pragma unroll
        for (int p = 0; p < 2; p++) {
            int lin = p * 256 + t;
            int r = lin >> 2, cc = (lin & 3) * 8;
            int ra = row0 + r; if (ra > M - 1) ra = M - 1;  // clamp (masked at store)
            gld_lds16(A + (size_t)ra * lda + k0 + cc, &lsA[lin * 8]);
            int rb = col0 + r;                               // N=1280 exact
            gld_lds16(Bt + (size_t)rb * K + k0 + cc, &lsB[lin * 8]);
        }
        __syncthreads();
        short8 af[4], bfr[4];
#pragma unroll
        for (int mt = 0; mt < 4; mt++)
            af[mt] = *(const short8*)&lsA[(mb + mt * 16 + lrow) * 32 + lk];
#pragma unroll
        for (int nt = 0; nt < 4; nt++)
            bfr[nt] = *(const short8*)&lsB[(nb + nt * 16 + lrow) * 32 + lk];
#pragma unroll
        for (int mt = 0; mt < 4; mt++)
#pragma unroll
            for (int nt = 0; nt < 4; nt++)
                acc[mt][nt] = __builtin_amdgcn_mfma_f32_16x16x32_bf16(
                    af[mt], bfr[nt], acc[mt][nt], 0, 0, 0);
    }
    const int quad = l >> 4, cl = l & 15;
#pragma unroll
    for (int nt = 0; nt < 4; nt++) {
        int col = col0 + nb + nt * 16 + cl;
        float bv = biasf ? biasf[col] : 0.f;
#pragma unroll
        for (int mt = 0; mt < 4; mt++)
#pragma unroll
            for (int r = 0; r < 4; r++) {
                int row = row0 + mb + mt * 16 + quad * 4 + r;
                if (row < M) {
                    if (F32OUT)
                        ((float*)Cout)[(size_t)row * 1280 + col] = acc[mt][nt][r] + bv;
                    else
                        ((ushort_t*)Cout)[(size_t)row * 1280 + col] = f2bf(acc[mt][nt][r] + bv);
                }
            }
    }
}

// q GEMM (x<64) fused with the 8 kv jobs (x=64..71). grid (72,10).
__global__ __launch_bounds__(256, 3) void gemm_q_kv(
    const ushort_t* __restrict__ hsb, const ushort_t* __restrict__ encb,
    const ushort_t* __restrict__ WqT,
    const ushort_t* __restrict__ WkT, const ushort_t* __restrict__ WvT,
    const ushort_t* __restrict__ WknT, const ushort_t* __restrict__ WvnT,
    ushort_t* __restrict__ qb, ushort_t* __restrict__ kb, ushort_t* __restrict__ vb,
    ushort_t* __restrict__ knb, ushort_t* __restrict__ vnb)
{
    int x = blockIdx.x, col0 = blockIdx.y * 128;
    if (x < 64) {
        gemm_body<false>(hsb, WqT, qb, nullptr, B_ * HW_, HID_, HID_, x * 128, col0);
        return;
    }
    int z = x - 64, kind = z & 1;
    const ushort_t* A; const ushort_t* Bt; ushort_t* C; int M;
    if (z < 4) {
        int bb = z >> 1;
        M = LTXT;
        A = encb + (size_t)bb * (LTXT + NTOK) * CAD_;
        Bt = kind ? WvT : WkT;
        C = (kind ? vb : kb) + (size_t)bb * LTXT * HID_;
    } else {
        int bb = (z - 4) >> 1;
        M = NTOK;
        A = encb + ((size_t)bb * (LTXT + NTOK) + LTXT) * CAD_;
        Bt = kind ? WvnT : WknT;
        C = (kind ? vnb : knb) + (size_t)bb * NTOK * HID_;
    }
    gemm_body<false>(A, Bt, C, nullptr, M, CAD_, CAD_, 0, col0);
}

__global__ __launch_bounds__(256, 3) void gemm_bt_f32(
    const ushort_t* __restrict__ A, const ushort_t* __restrict__ Bt,
    float* __restrict__ C, const float* __restrict__ biasf, int M, int K, int lda)
{
    gemm_body<true>(A, Bt, C, biasf, M, K, lda, blockIdx.x * 128, blockIdx.y * 128);
}

// ---------------- fused attention ----------------
// grid: (HW/128, NH, B). block 256 (4 waves x 32 queries).
// 96 padded keys: [0,77)=txt, [77,80)=zero, [80,84)=nested, [84,96)=zero.
// LDS 52.5 KB -> 3 blocks/CU (3 x 52.5 = 157.5 <= 160 KiB).
__global__ __launch_bounds__(256, 3) void attn_kernel(
    const ushort_t* __restrict__ qb, const ushort_t* __restrict__ kbf,
    const ushort_t* __restrict__ vbf, const ushort_t* __restrict__ knb,
    const ushort_t* __restrict__ vnb, const int* __restrict__ sidx,
    ushort_t* __restrict__ ob)
{
    const int qt = blockIdx.x, h = blockIdx.y, b = blockIdx.z;
    const int t = threadIdx.x, w = t >> 6, l = t & 63;
    const int s_idx = sidx[b];
    __shared__ ushort_t Kl[96 * 72];    // key-major, stride 72 (K extent 64 < 72)
    __shared__ ushort_t VT[64 * 104];   // dim-major (V^T), stride 104 (key extent 96 < 104)
    __shared__ ushort_t QP[128 * 104];  // Q phase: stride 72; P phase: stride 104

    // fill K (16B chunks)
    for (int id = t; id < 96 * 8; id += 256) {
        int key = id >> 3, c = (id & 7) * 8;
        uint4 v;
        if (key < LTXT)
            v = *(const uint4*)&kbf[((size_t)(b * LTXT + key)) * HID_ + h * HD_ + c];
        else if (key >= 80 && key < 80 + NTOK)
            v = *(const uint4*)&knb[((size_t)(b * NTOK + key - 80)) * HID_ + h * HD_ + c];
        else
            v = make_uint4(0u, 0u, 0u, 0u);
        *(uint4*)&Kl[key * 72 + c] = v;
    }
    // fill V^T (scalar; V is L1/L2 hot across q-tiles)
    for (int id = t; id < 64 * 96; id += 256) {
        int d = id / 96, key = id - d * 96;
        ushort_t val = 0;
        if (key < LTXT)
            val = vbf[((size_t)(b * LTXT + key)) * HID_ + h * HD_ + d];
        else if (key >= 80 && key < 80 + NTOK)
            val = vnb[((size_t)(b * NTOK + key - 80)) * HID_ + h * HD_ + d];
        VT[d * 104 + key] = val;
    }
    // fill Q tile (stride 72)
    const int q0 = qt * 128;
    for (int id = t; id < 128 * 8; id += 256) {
        int r = id >> 3, c = (id & 7) * 8;
        uint4 v = *(const uint4*)&qb[((size_t)(b * HW_ + q0 + r)) * HID_ + h * HD_ + c];
        *(uint4*)&QP[r * 72 + c] = v;
    }
    __syncthreads();

    const int mbw = w * 32, lrow = l & 15, lk = (l >> 4) * 8;
    const int quad = l >> 4, cl = l & 15;

    // S = Q K^T  (M=32 per wave, N=96, K=64)
    f32x4 S[2][6] = {};
#pragma unroll
    for (int ks = 0; ks < 2; ks++) {
        short8 af0 = *(const short8*)&QP[(mbw + lrow) * 72 + ks * 32 + lk];
        short8 af1 = *(const short8*)&QP[(mbw + 16 + lrow) * 72 + ks * 32 + lk];
#pragma unroll
        for (int nt = 0; nt < 6; nt++) {
            short8 bf = *(const short8*)&Kl[(nt * 16 + lrow) * 72 + ks * 32 + lk];
            S[0][nt] = __builtin_amdgcn_mfma_f32_16x16x32_bf16(af0, bf, S[0][nt], 0, 0, 0);
            S[1][nt] = __builtin_amdgcn_mfma_f32_16x16x32_bf16(af1, bf, S[1][nt], 0, 0, 0);
        }
    }
    __syncthreads();  // Q reads done before P overwrites the buffer

    const float sc = 0.125f;
#pragma unroll
    for (int mt = 0; mt < 2; mt++) {
#pragma unroll
        for (int r = 0; r < 4; r++) {
            float v[6];
#pragma unroll
            for (int nt = 0; nt < 6; nt++) v[nt] = S[mt][nt][r] * sc;
            float m = -1e30f;
#pragma unroll
            for (int nt = 0; nt < 5; nt++) {
                int c = nt * 16 + cl;
                if (c < LTXT) m = fmaxf(m, v[nt]);
            }
#pragma unroll
            for (int off = 1; off < 16; off <<= 1) m = fmaxf(m, __shfl_xor(m, off));
            float e[5], lsum = 0.f, wsn = 0.f;
#pragma unroll
            for (int nt = 0; nt < 5; nt++) {
                int c = nt * 16 + cl;
                float ev = (c < LTXT) ? __expf(v[nt] - m) : 0.f;
                e[nt] = ev; lsum += ev;
                if (c == s_idx) wsn += ev;
            }
#pragma unroll
            for (int off = 1; off < 16; off <<= 1) {
                lsum += __shfl_xor(lsum, off);
                wsn  += __shfl_xor(wsn, off);
            }
            float inv = 1.f / lsum;
            float ws = wsn * inv;
            bool nv = (cl < 4);
            float m5 = nv ? v[5] : -1e30f;
#pragma unroll
            for (int off = 1; off < 16; off <<= 1) m5 = fmaxf(m5, __shfl_xor(m5, off));
            float e5 = nv ? __expf(v[5] - m5) : 0.f;
            float l5 = e5;
#pragma unroll
            for (int off = 1; off < 16; off <<= 1) l5 += __shfl_xor(l5, off);
            float p5 = ws * e5 / l5;
            int row = mbw + mt * 16 + quad * 4 + r;
#pragma unroll
            for (int nt = 0; nt < 5; nt++) {
                int c = nt * 16 + cl;
                float p = (c < LTXT && c != s_idx) ? e[nt] * inv : 0.f;
                QP[row * 104 + c] = f2bf(p);
            }
            QP[row * 104 + 80 + cl] = f2bf(p5);
        }
    }
    __syncthreads();

    // O = P @ Vc  (M=32 per wave, N=64, K=96)
    f32x4 O[2][4] = {};
#pragma unroll
    for (int ks = 0; ks < 3; ks++) {
        short8 af0 = *(const short8*)&QP[(mbw + lrow) * 104 + ks * 32 + lk];
        short8 af1 = *(const short8*)&QP[(mbw + 16 + lrow) * 104 + ks * 32 + lk];
#pragma unroll
        for (int nt = 0; nt < 4; nt++) {
            short8 bf = *(const short8*)&VT[(nt * 16 + lrow) * 104 + ks * 32 + lk];
            O[0][nt] = __builtin_amdgcn_mfma_f32_16x16x32_bf16(af0, bf, O[0][nt], 0, 0, 0);
            O[1][nt] = __builtin_amdgcn_mfma_f32_16x16x32_bf16(af1, bf, O[1][nt], 0, 0, 0);
        }
    }
#pragma unroll
    for (int mt = 0; mt < 2; mt++)
#pragma unroll
        for (int nt = 0; nt < 4; nt++)
#pragma unroll
            for (int r = 0; r < 4; r++) {
                int row = mbw + mt * 16 + quad * 4 + r;
                int d = nt * 16 + cl;
                ob[((size_t)(b * HW_ + q0 + row)) * HID_ + h * HD_ + d] = f2bf(O[mt][nt][r]);
            }
}

// ---------------- launch ----------------
extern "C" void kernel_launch(void* const* d_in, const int* in_sizes, int n_in,
                              void* d_out, int out_size, void* d_ws, size_t ws_size,
                              hipStream_t stream) {
    const float* hs   = (const float*)d_in[0];
    const float* enc  = (const float*)d_in[1];
    const int*   idx  = (const int*)d_in[2];
    const float* Wq   = (const float*)d_in[3];
    const float* Wk   = (const float*)d_in[4];
    const float* Wv   = (const float*)d_in[5];
    const float* Wkn  = (const float*)d_in[6];
    const float* Wvn  = (const float*)d_in[7];
    const float* Wout = (const float*)d_in[8];
    const float* bout = (const float*)d_in[9];
    float* out = (float*)d_out;

    ushort_t* ws = (ushort_t*)d_ws;
    size_t o = 0;
    ushort_t* WqT   = ws + o; o += (size_t)1280 * 1280;
    ushort_t* WkT   = ws + o; o += (size_t)1280 * 2048;
    ushort_t* WvT   = ws + o; o += (size_t)1280 * 2048;
    ushort_t* WknT  = ws + o; o += (size_t)1280 * 2048;
    ushort_t* WvnT  = ws + o; o += (size_t)1280 * 2048;
    ushort_t* WoutT = ws + o; o += (size_t)1280 * 1280;
    ushort_t* hsb   = ws + o; o += (size_t)B_ * HW_ * HID_;
    ushort_t* encb  = ws + o; o += (size_t)B_ * (LTXT + NTOK) * CAD_;
    ushort_t* qbuf  = ws + o; o += (size_t)B_ * HW_ * HID_;
    ushort_t* kbuf  = ws + o; o += (size_t)B_ * LTXT * HID_;
    ushort_t* vbuf  = ws + o; o += (size_t)B_ * LTXT * HID_;
    ushort_t* knbuf = ws + o; o += (size_t)B_ * NTOK * HID_;
    ushort_t* vnbuf = ws + o; o += (size_t)B_ * NTOK * HID_;
    ushort_t* attnb = hsb;  // alias: hsb dead after gemm_q_kv

    prep<<<dim3(2560, 8), 256, 0, stream>>>(hs, enc, Wq, Wk, Wv, Wkn, Wvn, Wout,
                                            hsb, encb,
                                            WqT, WkT, WvT, WknT, WvnT, WoutT);
    gemm_q_kv<<<dim3(72, 10), 256, 0, stream>>>(hsb, encb, WqT, WkT, WvT, WknT, WvnT,
                                                qbuf, kbuf, vbuf, knbuf, vnbuf);
    attn_kernel<<<dim3(HW_ / 128, NH_, B_), 256, 0, stream>>>(qbuf, kbuf, vbuf,
                                                              knbuf, vnbuf, idx, attnb);
    gemm_bt_f32<<<dim3(64, 10), 256, 0, stream>>>(attnb, WoutT, out, bout,
                                                  B_ * HW_, HID_, HID_);
}